// Round 2
// 182.437 us; speedup vs baseline: 1.0526x; 1.0526x over previous
//
#include <hip/hip_runtime.h>
#include <stdint.h>

typedef unsigned short u16;
typedef __attribute__((ext_vector_type(8))) __bf16 bvec8;
typedef __attribute__((ext_vector_type(4))) float f32x4;

__device__ __forceinline__ u16 f32_to_bf16(float f) {
    uint32_t u = __float_as_uint(f);
    u += 0x7fffu + ((u >> 16) & 1u);   // RNE
    return (u16)(u >> 16);
}

// async global->LDS, 16B/lane; LDS dest = wave-uniform base + lane*16 (HW rule)
__device__ __forceinline__ void gl2lds16(const u16* g, u16* l) {
    void* gnc = const_cast<void*>((const void*)g);
    __builtin_amdgcn_global_load_lds(
        (__attribute__((address_space(1))) uint32_t*)gnc,
        (__attribute__((address_space(3))) uint32_t*)((void*)l),
        16, 0, 0);
}

// ---------------------------------------------------------------------------
// fp32 -> bf16 for all three inputs in one launch
// ---------------------------------------------------------------------------
__global__ __launch_bounds__(256) void cvt3(
    const float* __restrict__ a, int na4, const float* __restrict__ b, int nb4,
    const float* __restrict__ c, int nc4,
    u16* __restrict__ oa, u16* __restrict__ ob, u16* __restrict__ oc)
{
    int i = blockIdx.x * 256 + threadIdx.x;
    const float* src; u16* dst; int off;
    if (i < na4)             { src = a; dst = oa; off = i; }
    else if (i < na4 + nb4)  { src = b; dst = ob; off = i - na4; }
    else if (i < na4 + nb4 + nc4) { src = c; dst = oc; off = i - na4 - nb4; }
    else return;
    float4 v = ((const float4*)src)[off];
    ushort4 o;
    o.x = f32_to_bf16(v.x); o.y = f32_to_bf16(v.y);
    o.z = f32_to_bf16(v.z); o.w = f32_to_bf16(v.w);
    ((ushort4*)dst)[off] = o;
}

// ---------------------------------------------------------------------------
// GEMM (B^T): C[M][N] = A[M][K]*B[N][K]^T + bias[N]; bf16 in, fp32 acc.
// BM=128, BK=32, BNt template (128 or 64). 256 thr = 4 waves as 2x2.
// ---------------------------------------------------------------------------
template <int BNt, bool OUT_BF16>
__global__ __launch_bounds__(256) void gemm_bt_bias(
    const u16* __restrict__ A, const u16* __restrict__ B,
    const float* __restrict__ bias, void* __restrict__ Cv,
    int M, int N, int K)
{
    constexpr int NT = BNt / 32;                 // n-frags per wave
    __shared__ __attribute__((aligned(16))) u16 As[128 * 32];
    __shared__ __attribute__((aligned(16))) u16 Bs[BNt * 32];

    const int tid = threadIdx.x, wave = tid >> 6, lane = tid & 63;
    const int col = lane & 15, quad = lane >> 4;
    const int m0 = blockIdx.y * 128, n0 = blockIdx.x * BNt;
    const int wm = (wave >> 1) * 64, wn = (wave & 1) * (BNt / 2);
    const int srow = lane >> 2, schunk = lane & 3;
    const u16* Ag = A + (size_t)(m0 + wave * 32) * K;

    f32x4 acc[4][NT];
#pragma unroll
    for (int i = 0; i < 4; i++)
#pragma unroll
        for (int j = 0; j < NT; j++) acc[i][j] = f32x4{0.f, 0.f, 0.f, 0.f};

    for (int k0 = 0; k0 < K; k0 += 32) {
        __syncthreads();
        gl2lds16(Ag + (size_t)(srow)      * K + k0 + schunk * 8, &As[(wave * 2 + 0) * 512]);
        gl2lds16(Ag + (size_t)(16 + srow) * K + k0 + schunk * 8, &As[(wave * 2 + 1) * 512]);
        if constexpr (BNt == 128) {
            const u16* Bg = B + (size_t)(n0 + wave * 32) * K;
            gl2lds16(Bg + (size_t)(srow)      * K + k0 + schunk * 8, &Bs[(wave * 2 + 0) * 512]);
            gl2lds16(Bg + (size_t)(16 + srow) * K + k0 + schunk * 8, &Bs[(wave * 2 + 1) * 512]);
        } else {
            const u16* Bg = B + (size_t)(n0 + wave * 16) * K;
            gl2lds16(Bg + (size_t)(srow)      * K + k0 + schunk * 8, &Bs[wave * 512]);
        }
        __syncthreads();

        bvec8 af[4], bfv[NT];
#pragma unroll
        for (int mt = 0; mt < 4; mt++)  af[mt]  = *(const bvec8*)&As[(wm + mt * 16 + col) * 32 + quad * 8];
#pragma unroll
        for (int nt = 0; nt < NT; nt++) bfv[nt] = *(const bvec8*)&Bs[(wn + nt * 16 + col) * 32 + quad * 8];
#pragma unroll
        for (int mt = 0; mt < 4; mt++)
#pragma unroll
            for (int nt = 0; nt < NT; nt++)
                acc[mt][nt] = __builtin_amdgcn_mfma_f32_16x16x32_bf16(af[mt], bfv[nt], acc[mt][nt], 0, 0, 0);
    }

#pragma unroll
    for (int mt = 0; mt < 4; mt++) {
#pragma unroll
        for (int r = 0; r < 4; r++) {
            const int m = m0 + wm + mt * 16 + quad * 4 + r;
#pragma unroll
            for (int nt = 0; nt < NT; nt++) {
                const int n = n0 + wn + nt * 16 + col;
                float v = acc[mt][nt][r] + bias[n];
                if (OUT_BF16) ((u16*)Cv)[(size_t)m * N + n] = f32_to_bf16(v);
                else          ((float*)Cv)[(size_t)m * N + n] = v;
            }
        }
    }
}

// ---------------------------------------------------------------------------
// V transpose: qkv V-region [b][t][h*64+d] -> vT[b][h][d][t]  (bf16)
// ---------------------------------------------------------------------------
__global__ __launch_bounds__(256) void transpose_v(const u16* __restrict__ qkv,
                                                   u16* __restrict__ vT)
{
    __shared__ u16 Ts[64 * 74];
    const int tid = threadIdx.x;
    const int t0 = blockIdx.x * 64, h = blockIdx.y, b = blockIdx.z;
    const u16* src = qkv + (size_t)b * 2048 * 3072 + 2048 + h * 64;
#pragma unroll
    for (int k2 = 0; k2 < 2; k2++) {
        int c = k2 * 256 + tid, tl = c >> 3, ch = c & 7;
        *(uint4*)&Ts[tl * 74 + ch * 8] = *(const uint4*)(src + (size_t)(t0 + tl) * 3072 + ch * 8);
    }
    __syncthreads();
    u16* dst = vT + (size_t)((b * 16 + h) * 64) * 2048;
#pragma unroll
    for (int k2 = 0; k2 < 2; k2++) {
        int c = k2 * 256 + tid, d = c >> 3, tch = c & 7;
        u16 tmp[8];
#pragma unroll
        for (int j2 = 0; j2 < 8; j2++) tmp[j2] = Ts[(tch * 8 + j2) * 74 + d];
        *(uint4*)&dst[(size_t)d * 2048 + t0 + tch * 8] = *(const uint4*)tmp;
    }
}

// ---------------------------------------------------------------------------
// Flash attention, no-max softmax. Complementary pair (s,31-s) per block.
// Grid (32,16,1): x = b*16+h  =>  all 16 blocks of a head share one XCD
// (linear%8 = x%8) so K/V live in that XCD's L2.
// K/V double-buffered via global_load_lds + raw s_barrier/s_waitcnt vmcnt(4).
//
// REGISTER-P VERSION: S^T = mfma(K,Q) so each lane holds P for ONE Q-row
// (col) at staged-K rows nt*16+quad*4+r. K staging rows are permuted by
//   tau(16a+4q+r) = 32*(a>>1) + 8q + 4*(a&1) + r
// so the lane's 16 P values are exactly the A-fragment k-slots
// (ks*32+quad*8+j) that the unchanged b128 V fragments expect.
// P->bf16 via plain compiler casts (backend emits correct RNE cvt_pk;
// hand-written asm cvt_pk was the round-1 correctness suspect and is
// also slower per guide m240). P never touches LDS.
// ---------------------------------------------------------------------------
__global__ __launch_bounds__(256) void attn_kernel(const u16* __restrict__ qkv,
                                                   const u16* __restrict__ vT,
                                                   u16* __restrict__ Y)
{
    __shared__ __attribute__((aligned(16))) u16 Qs[64 * 64];
    __shared__ __attribute__((aligned(16))) u16 Ks[2][64 * 64];
    __shared__ __attribute__((aligned(16))) u16 Vs[2][64 * 64];

    const int tid = threadIdx.x, wave = tid >> 6, lane = tid & 63;
    const int col = lane & 15, quad = lane >> 4;

    const int g = blockIdx.x;                // b*16 + h
    const int b = g >> 4, h = g & 15;
    const int s_idx = blockIdx.y;            // pair (s_idx, 31-s_idx)

    const u16* qb = qkv + (size_t)b * 2048 * 3072;
    const u16* vb = vT + (size_t)g * 64 * 2048;

    // per-lane swizzled source params for the 2 staging calls per tile
    const int c0 = wave * 64 + lane, c1 = 256 + c0;
    const int r0 = c0 >> 3, p0 = c0 & 7, r1 = c1 >> 3, p1 = c1 & 7;
    const int sw0 = (p0 ^ (r0 & 7)) * 8, sw1 = (p1 ^ (r1 & 7)) * 8;
    // K-row staging permutation: staged row rho holds logical row tau(rho)
    const int tau0 = (r0 & 32) | ((r0 & 12) << 1) | ((r0 & 16) >> 2) | (r0 & 3);
    const int tau1 = (r1 & 32) | ((r1 & 12) << 1) | ((r1 & 16) >> 2) | (r1 & 3);

    const int q8 = quad * 8;
    const int qit = wave * 16 + col;         // in-tile Q row this lane owns

#pragma unroll
    for (int phase = 0; phase < 2; ++phase) {
        const int qt = phase ? (31 - s_idx) : s_idx;
        const int q0 = qt * 64;

        __syncthreads();   // phase-0 readers done; also drains Y stores
        gl2lds16(qb + (size_t)(q0 + r0) * 3072 + h * 64 + sw0, &Qs[wave * 512]);
        gl2lds16(qb + (size_t)(q0 + r1) * 3072 + h * 64 + sw1, &Qs[2048 + wave * 512]);
        __syncthreads();   // Q visible to all waves

        const int qrow = wave * 16 + col;
        bvec8 qf0 = *(const bvec8*)&Qs[qrow * 64 + ((quad       ^ (qrow & 7)) * 8)];
        bvec8 qf1 = *(const bvec8*)&Qs[qrow * 64 + (((4 + quad) ^ (qrow & 7)) * 8)];

        float l_acc = 0.f;
        f32x4 o[4];
#pragma unroll
        for (int d = 0; d < 4; d++) o[d] = f32x4{0.f, 0.f, 0.f, 0.f};

        // prologue: issue tile 0 into buffer 0 (K rows tau-permuted)
        {
            gl2lds16(qb + (size_t)(tau0) * 3072 + 1024 + h * 64 + sw0, &Ks[0][wave * 512]);
            gl2lds16(qb + (size_t)(tau1) * 3072 + 1024 + h * 64 + sw1, &Ks[0][2048 + wave * 512]);
            gl2lds16(vb + (size_t)r0 * 2048 + sw0, &Vs[0][wave * 512]);
            gl2lds16(vb + (size_t)r1 * 2048 + sw1, &Vs[0][2048 + wave * 512]);
        }

        for (int kt = 0; kt <= qt; ++kt) {
            const int cur = kt & 1;
            if (kt < qt) {
                const int s0n = (kt + 1) * 64;
                const int nb2 = cur ^ 1;
                gl2lds16(qb + (size_t)(s0n + tau0) * 3072 + 1024 + h * 64 + sw0, &Ks[nb2][wave * 512]);
                gl2lds16(qb + (size_t)(s0n + tau1) * 3072 + 1024 + h * 64 + sw1, &Ks[nb2][2048 + wave * 512]);
                gl2lds16(vb + (size_t)r0 * 2048 + s0n + sw0, &Vs[nb2][wave * 512]);
                gl2lds16(vb + (size_t)r1 * 2048 + s0n + sw1, &Vs[nb2][2048 + wave * 512]);
                asm volatile("s_waitcnt vmcnt(4)" ::: "memory");   // cur tile landed; next in flight
            } else {
                asm volatile("s_waitcnt vmcnt(0)" ::: "memory");   // last tile landed
            }
            asm volatile("s_barrier" ::: "memory");                 // all waves see cur tile

            // S^T = K Q^T : lane (quad,col) reg r of sv[nt] =
            //   S[q = wave*16+col][staged k = nt*16+quad*4+r]
            f32x4 sv[4];
#pragma unroll
            for (int nt = 0; nt < 4; nt++) {
                const int krow = nt * 16 + col;
                bvec8 kf0 = *(const bvec8*)&Ks[cur][krow * 64 + ((quad       ^ (krow & 7)) * 8)];
                bvec8 kf1 = *(const bvec8*)&Ks[cur][krow * 64 + (((4 + quad) ^ (krow & 7)) * 8)];
                sv[nt] = f32x4{0.f, 0.f, 0.f, 0.f};
                sv[nt] = __builtin_amdgcn_mfma_f32_16x16x32_bf16(kf0, qf0, sv[nt], 0, 0, 0);
                sv[nt] = __builtin_amdgcn_mfma_f32_16x16x32_bf16(kf1, qf1, sv[nt], 0, 0, 0);
            }

            // no-max softmax in registers: p = exp(S/8); mask diag by LOGICAL k.
            // Element j of pbv[ks] must be P[q=col][t = ks*32 + quad*8 + j]:
            // nt=2ks  -> j = r      (klog = ks*32 + quad*8 + r)
            // nt=2ks+1-> j = 4 + r  (klog = ks*32 + quad*8 + 4 + r)
            const bool diag = (kt == qt);
            bvec8 pbv[2];
#pragma unroll
            for (int nt = 0; nt < 4; nt++) {
#pragma unroll
                for (int r = 0; r < 4; r++) {
                    float p = __expf(sv[nt][r] * 0.125f);
                    const int klog = 32 * (nt >> 1) + q8 + 4 * (nt & 1) + r;
                    if (diag && klog > qit) p = 0.f;
                    l_acc += p;
                    pbv[nt >> 1][(nt & 1) * 4 + r] = (__bf16)p;
                }
            }

            // O += P V   (P straight from registers; V reads unchanged b128)
#pragma unroll
            for (int ks = 0; ks < 2; ks++) {
#pragma unroll
                for (int d = 0; d < 4; d++) {
                    const int vrow = d * 16 + col;
                    bvec8 vf = *(const bvec8*)&Vs[cur][vrow * 64 + (((ks * 4 + quad) ^ (vrow & 7)) * 8)];
                    o[d] = __builtin_amdgcn_mfma_f32_16x16x32_bf16(pbv[ks], vf, o[d], 0, 0, 0);
                }
            }
            asm volatile("s_barrier" ::: "memory");   // readers done before buf reuse
        }

        // l lives per-lane for Q-row = col: reduce across quads, then
        // redistribute to the O layout (rows quad*4+r) and store.
        float l = l_acc;
        l += __shfl_xor(l, 16);
        l += __shfl_xor(l, 32);
#pragma unroll
        for (int r = 0; r < 4; r++) {
            const float lr = __shfl(l, quad * 4 + r);   // lane quad*4+r holds row quad*4+r
            const float inv = 1.0f / lr;
            const int t = q0 + wave * 16 + quad * 4 + r;
#pragma unroll
            for (int d = 0; d < 4; d++)
                Y[(size_t)(b * 2048 + t) * 1024 + h * 64 + d * 16 + col] =
                    f32_to_bf16(o[d][r] * inv);
        }
    }
}

// ---------------------------------------------------------------------------
extern "C" void kernel_launch(void* const* d_in, const int* in_sizes, int n_in,
                              void* d_out, int out_size, void* d_ws, size_t ws_size,
                              hipStream_t stream) {
    const float* x      = (const float*)d_in[0];
    const float* w_attn = (const float*)d_in[1];
    const float* b_attn = (const float*)d_in[2];
    const float* w_proj = (const float*)d_in[3];
    const float* b_proj = (const float*)d_in[4];
    float* out = (float*)d_out;

    // ws (u16 elements): xb 4096x1024 | wab 3072x1024 | wpb 1024x1024 |
    //                    qkv 4096x3072 | y 4096x1024 ; vT overlays xb (dead after GEMM1)
    u16* xb  = (u16*)d_ws;
    u16* wab = xb  + (size_t)4096 * 1024;
    u16* wpb = wab + (size_t)3072 * 1024;
    u16* qkv = wpb + (size_t)1024 * 1024;
    u16* y   = qkv + (size_t)4096 * 3072;
    u16* vT  = xb;                               // reuse: 2*16*64*2048 = 4096*1024

    const int na4 = 4096 * 1024 / 4, nb4 = 3072 * 1024 / 4, nc4 = 1024 * 1024 / 4;
    cvt3<<<(na4 + nb4 + nc4 + 255) / 256, 256, 0, stream>>>(
        x, na4, w_attn, nb4, w_proj, nc4, xb, wab, wpb);

    dim3 g1(3072 / 128, 4096 / 128);
    gemm_bt_bias<128, true><<<g1, 256, 0, stream>>>(xb, wab, b_attn, qkv, 4096, 3072, 1024);

    dim3 gt(32, 16, 2);
    transpose_v<<<gt, 256, 0, stream>>>(qkv, vT);

    dim3 g2(32, 16, 1);   // x = b*16+h (XCD-local K/V), y = pair index
    attn_kernel<<<g2, 256, 0, stream>>>(qkv, vT, y);

    dim3 g3(1024 / 64, 4096 / 128);
    gemm_bt_bias<64, false><<<g3, 256, 0, stream>>>(y, wpb, b_proj, out, 4096, 1024, 1024);
}

// Round 3
// 181.459 us; speedup vs baseline: 1.0582x; 1.0054x over previous
//
#include <hip/hip_runtime.h>
#include <stdint.h>

typedef unsigned short u16;
typedef __attribute__((ext_vector_type(8))) __bf16 bvec8;
typedef __attribute__((ext_vector_type(4))) float f32x4;

__device__ __forceinline__ u16 f32_to_bf16(float f) {
    uint32_t u = __float_as_uint(f);
    u += 0x7fffu + ((u >> 16) & 1u);   // RNE
    return (u16)(u >> 16);
}

// async global->LDS, 16B/lane; LDS dest = wave-uniform base + lane*16 (HW rule)
__device__ __forceinline__ void gl2lds16(const u16* g, u16* l) {
    void* gnc = const_cast<void*>((const void*)g);
    __builtin_amdgcn_global_load_lds(
        (__attribute__((address_space(1))) uint32_t*)gnc,
        (__attribute__((address_space(3))) uint32_t*)((void*)l),
        16, 0, 0);
}

// ---------------------------------------------------------------------------
// fp32 -> bf16 for all three inputs in one launch
// ---------------------------------------------------------------------------
__global__ __launch_bounds__(256) void cvt3(
    const float* __restrict__ a, int na4, const float* __restrict__ b, int nb4,
    const float* __restrict__ c, int nc4,
    u16* __restrict__ oa, u16* __restrict__ ob, u16* __restrict__ oc)
{
    int i = blockIdx.x * 256 + threadIdx.x;
    const float* src; u16* dst; int off;
    if (i < na4)             { src = a; dst = oa; off = i; }
    else if (i < na4 + nb4)  { src = b; dst = ob; off = i - na4; }
    else if (i < na4 + nb4 + nc4) { src = c; dst = oc; off = i - na4 - nb4; }
    else return;
    float4 v = ((const float4*)src)[off];
    ushort4 o;
    o.x = f32_to_bf16(v.x); o.y = f32_to_bf16(v.y);
    o.z = f32_to_bf16(v.z); o.w = f32_to_bf16(v.w);
    ((ushort4*)dst)[off] = o;
}

// ---------------------------------------------------------------------------
// GEMM (B^T): C[M][N] = A[M][K]*B[N][K]^T + bias[N]; bf16 in, fp32 acc.
// BM=128, BK=32, BNt template (128 or 64). 256 thr = 4 waves as 2x2.
// DOUBLE-BUFFERED: stage tile t+1 while computing tile t; counted
// s_waitcnt vmcnt(N) (never 0 mid-loop) + raw s_barrier — the exact
// pattern proven in attn_kernel below. Removes the per-step global->LDS
// latency drain that the old sync/stage/sync/compute loop paid.
// ---------------------------------------------------------------------------
template <int BNt, bool OUT_BF16>
__global__ __launch_bounds__(256) void gemm_bt_bias(
    const u16* __restrict__ A, const u16* __restrict__ B,
    const float* __restrict__ bias, void* __restrict__ Cv,
    int M, int N, int K)
{
    constexpr int NT = BNt / 32;                 // n-frags per wave
    __shared__ __attribute__((aligned(16))) u16 As[2][128 * 32];
    __shared__ __attribute__((aligned(16))) u16 Bs[2][BNt * 32];

    const int tid = threadIdx.x, wave = tid >> 6, lane = tid & 63;
    const int col = lane & 15, quad = lane >> 4;
    const int m0 = blockIdx.y * 128, n0 = blockIdx.x * BNt;
    const int wm = (wave >> 1) * 64, wn = (wave & 1) * (BNt / 2);
    const int srow = lane >> 2, schunk = lane & 3;
    const u16* Ag = A + (size_t)(m0 + wave * 32) * K;
    const u16* Bg = B + (size_t)(n0 + wave * (BNt == 128 ? 32 : 16)) * K;

    f32x4 acc[4][NT];
#pragma unroll
    for (int i = 0; i < 4; i++)
#pragma unroll
        for (int j = 0; j < NT; j++) acc[i][j] = f32x4{0.f, 0.f, 0.f, 0.f};

    auto stage = [&](int bb, int k0) {
        gl2lds16(Ag + (size_t)(srow)      * K + k0 + schunk * 8, &As[bb][(wave * 2 + 0) * 512]);
        gl2lds16(Ag + (size_t)(16 + srow) * K + k0 + schunk * 8, &As[bb][(wave * 2 + 1) * 512]);
        if constexpr (BNt == 128) {
            gl2lds16(Bg + (size_t)(srow)      * K + k0 + schunk * 8, &Bs[bb][(wave * 2 + 0) * 512]);
            gl2lds16(Bg + (size_t)(16 + srow) * K + k0 + schunk * 8, &Bs[bb][(wave * 2 + 1) * 512]);
        } else {
            gl2lds16(Bg + (size_t)(srow)      * K + k0 + schunk * 8, &Bs[bb][wave * 512]);
        }
    };

    // prologue: tile 0 into buffer 0
    stage(0, 0);
    const int NS = K / 32;

    for (int t = 0; t < NS; ++t) {
        const int cur = t & 1;
        if (t + 1 < NS) {
            stage(cur ^ 1, (t + 1) * 32);
            if constexpr (BNt == 128) asm volatile("s_waitcnt vmcnt(4)" ::: "memory");
            else                      asm volatile("s_waitcnt vmcnt(3)" ::: "memory");
        } else {
            asm volatile("s_waitcnt vmcnt(0)" ::: "memory");
        }
        asm volatile("s_barrier" ::: "memory");     // cur tile visible to all waves

        bvec8 af[4], bfv[NT];
#pragma unroll
        for (int mt = 0; mt < 4; mt++)  af[mt]  = *(const bvec8*)&As[cur][(wm + mt * 16 + col) * 32 + quad * 8];
#pragma unroll
        for (int nt = 0; nt < NT; nt++) bfv[nt] = *(const bvec8*)&Bs[cur][(wn + nt * 16 + col) * 32 + quad * 8];
#pragma unroll
        for (int mt = 0; mt < 4; mt++)
#pragma unroll
            for (int nt = 0; nt < NT; nt++)
                acc[mt][nt] = __builtin_amdgcn_mfma_f32_16x16x32_bf16(af[mt], bfv[nt], acc[mt][nt], 0, 0, 0);

        asm volatile("s_barrier" ::: "memory");     // readers done before buf reuse
    }

#pragma unroll
    for (int mt = 0; mt < 4; mt++) {
#pragma unroll
        for (int r = 0; r < 4; r++) {
            const int m = m0 + wm + mt * 16 + quad * 4 + r;
#pragma unroll
            for (int nt = 0; nt < NT; nt++) {
                const int n = n0 + wn + nt * 16 + col;
                float v = acc[mt][nt][r] + bias[n];
                if (OUT_BF16) ((u16*)Cv)[(size_t)m * N + n] = f32_to_bf16(v);
                else          ((float*)Cv)[(size_t)m * N + n] = v;
            }
        }
    }
}

// ---------------------------------------------------------------------------
// V transpose: qkv V-region [b][t][h*64+d] -> vT[b][h][d][t]  (bf16)
// ---------------------------------------------------------------------------
__global__ __launch_bounds__(256) void transpose_v(const u16* __restrict__ qkv,
                                                   u16* __restrict__ vT)
{
    __shared__ u16 Ts[64 * 74];
    const int tid = threadIdx.x;
    const int t0 = blockIdx.x * 64, h = blockIdx.y, b = blockIdx.z;
    const u16* src = qkv + (size_t)b * 2048 * 3072 + 2048 + h * 64;
#pragma unroll
    for (int k2 = 0; k2 < 2; k2++) {
        int c = k2 * 256 + tid, tl = c >> 3, ch = c & 7;
        *(uint4*)&Ts[tl * 74 + ch * 8] = *(const uint4*)(src + (size_t)(t0 + tl) * 3072 + ch * 8);
    }
    __syncthreads();
    u16* dst = vT + (size_t)((b * 16 + h) * 64) * 2048;
#pragma unroll
    for (int k2 = 0; k2 < 2; k2++) {
        int c = k2 * 256 + tid, d = c >> 3, tch = c & 7;
        u16 tmp[8];
#pragma unroll
        for (int j2 = 0; j2 < 8; j2++) tmp[j2] = Ts[(tch * 8 + j2) * 74 + d];
        *(uint4*)&dst[(size_t)d * 2048 + t0 + tch * 8] = *(const uint4*)tmp;
    }
}

// ---------------------------------------------------------------------------
// Flash attention, no-max softmax. Complementary pair (s,31-s) per block.
// Grid (32,16,1): x = b*16+h  =>  all 16 blocks of a head share one XCD
// (linear%8 = x%8) so K/V live in that XCD's L2.
// K/V double-buffered via global_load_lds + raw s_barrier/s_waitcnt vmcnt(4).
//
// REGISTER-P VERSION: S^T = mfma(K,Q) so each lane holds P for ONE Q-row
// (col) at staged-K rows nt*16+quad*4+r. K staging rows are permuted by
//   tau(16a+4q+r) = 32*(a>>1) + 8q + 4*(a&1) + r
// so the lane's 16 P values are exactly the A-fragment k-slots
// (ks*32+quad*8+j) that the unchanged b128 V fragments expect.
// P->bf16 via plain compiler casts (backend emits correct RNE cvt_pk;
// hand-written asm cvt_pk was the round-1 correctness bug and is also
// slower per guide m240). P never touches LDS.
// ---------------------------------------------------------------------------
__global__ __launch_bounds__(256) void attn_kernel(const u16* __restrict__ qkv,
                                                   const u16* __restrict__ vT,
                                                   u16* __restrict__ Y)
{
    __shared__ __attribute__((aligned(16))) u16 Qs[64 * 64];
    __shared__ __attribute__((aligned(16))) u16 Ks[2][64 * 64];
    __shared__ __attribute__((aligned(16))) u16 Vs[2][64 * 64];

    const int tid = threadIdx.x, wave = tid >> 6, lane = tid & 63;
    const int col = lane & 15, quad = lane >> 4;

    const int g = blockIdx.x;                // b*16 + h
    const int b = g >> 4, h = g & 15;
    const int s_idx = blockIdx.y;            // pair (s_idx, 31-s_idx)

    const u16* qb = qkv + (size_t)b * 2048 * 3072;
    const u16* vb = vT + (size_t)g * 64 * 2048;

    // per-lane swizzled source params for the 2 staging calls per tile
    const int c0 = wave * 64 + lane, c1 = 256 + c0;
    const int r0 = c0 >> 3, p0 = c0 & 7, r1 = c1 >> 3, p1 = c1 & 7;
    const int sw0 = (p0 ^ (r0 & 7)) * 8, sw1 = (p1 ^ (r1 & 7)) * 8;
    // K-row staging permutation: staged row rho holds logical row tau(rho)
    const int tau0 = (r0 & 32) | ((r0 & 12) << 1) | ((r0 & 16) >> 2) | (r0 & 3);
    const int tau1 = (r1 & 32) | ((r1 & 12) << 1) | ((r1 & 16) >> 2) | (r1 & 3);

    const int q8 = quad * 8;
    const int qit = wave * 16 + col;         // in-tile Q row this lane owns

#pragma unroll
    for (int phase = 0; phase < 2; ++phase) {
        const int qt = phase ? (31 - s_idx) : s_idx;
        const int q0 = qt * 64;

        __syncthreads();   // phase-0 readers done; also drains Y stores
        gl2lds16(qb + (size_t)(q0 + r0) * 3072 + h * 64 + sw0, &Qs[wave * 512]);
        gl2lds16(qb + (size_t)(q0 + r1) * 3072 + h * 64 + sw1, &Qs[2048 + wave * 512]);
        __syncthreads();   // Q visible to all waves

        const int qrow = wave * 16 + col;
        bvec8 qf0 = *(const bvec8*)&Qs[qrow * 64 + ((quad       ^ (qrow & 7)) * 8)];
        bvec8 qf1 = *(const bvec8*)&Qs[qrow * 64 + (((4 + quad) ^ (qrow & 7)) * 8)];

        float l_acc = 0.f;
        f32x4 o[4];
#pragma unroll
        for (int d = 0; d < 4; d++) o[d] = f32x4{0.f, 0.f, 0.f, 0.f};

        // prologue: issue tile 0 into buffer 0 (K rows tau-permuted)
        {
            gl2lds16(qb + (size_t)(tau0) * 3072 + 1024 + h * 64 + sw0, &Ks[0][wave * 512]);
            gl2lds16(qb + (size_t)(tau1) * 3072 + 1024 + h * 64 + sw1, &Ks[0][2048 + wave * 512]);
            gl2lds16(vb + (size_t)r0 * 2048 + sw0, &Vs[0][wave * 512]);
            gl2lds16(vb + (size_t)r1 * 2048 + sw1, &Vs[0][2048 + wave * 512]);
        }

        for (int kt = 0; kt <= qt; ++kt) {
            const int cur = kt & 1;
            if (kt < qt) {
                const int s0n = (kt + 1) * 64;
                const int nb2 = cur ^ 1;
                gl2lds16(qb + (size_t)(s0n + tau0) * 3072 + 1024 + h * 64 + sw0, &Ks[nb2][wave * 512]);
                gl2lds16(qb + (size_t)(s0n + tau1) * 3072 + 1024 + h * 64 + sw1, &Ks[nb2][2048 + wave * 512]);
                gl2lds16(vb + (size_t)r0 * 2048 + s0n + sw0, &Vs[nb2][wave * 512]);
                gl2lds16(vb + (size_t)r1 * 2048 + s0n + sw1, &Vs[nb2][2048 + wave * 512]);
                asm volatile("s_waitcnt vmcnt(4)" ::: "memory");   // cur tile landed; next in flight
            } else {
                asm volatile("s_waitcnt vmcnt(0)" ::: "memory");   // last tile landed
            }
            asm volatile("s_barrier" ::: "memory");                 // all waves see cur tile

            // S^T = K Q^T : lane (quad,col) reg r of sv[nt] =
            //   S[q = wave*16+col][staged k = nt*16+quad*4+r]
            f32x4 sv[4];
#pragma unroll
            for (int nt = 0; nt < 4; nt++) {
                const int krow = nt * 16 + col;
                bvec8 kf0 = *(const bvec8*)&Ks[cur][krow * 64 + ((quad       ^ (krow & 7)) * 8)];
                bvec8 kf1 = *(const bvec8*)&Ks[cur][krow * 64 + (((4 + quad) ^ (krow & 7)) * 8)];
                sv[nt] = f32x4{0.f, 0.f, 0.f, 0.f};
                sv[nt] = __builtin_amdgcn_mfma_f32_16x16x32_bf16(kf0, qf0, sv[nt], 0, 0, 0);
                sv[nt] = __builtin_amdgcn_mfma_f32_16x16x32_bf16(kf1, qf1, sv[nt], 0, 0, 0);
            }

            // no-max softmax in registers: p = exp(S/8); mask diag by LOGICAL k.
            // Element j of pbv[ks] must be P[q=col][t = ks*32 + quad*8 + j]:
            // nt=2ks  -> j = r      (klog = ks*32 + quad*8 + r)
            // nt=2ks+1-> j = 4 + r  (klog = ks*32 + quad*8 + 4 + r)
            const bool diag = (kt == qt);
            bvec8 pbv[2];
#pragma unroll
            for (int nt = 0; nt < 4; nt++) {
#pragma unroll
                for (int r = 0; r < 4; r++) {
                    float p = __expf(sv[nt][r] * 0.125f);
                    const int klog = 32 * (nt >> 1) + q8 + 4 * (nt & 1) + r;
                    if (diag && klog > qit) p = 0.f;
                    l_acc += p;
                    pbv[nt >> 1][(nt & 1) * 4 + r] = (__bf16)p;
                }
            }

            // O += P V   (P straight from registers; V reads unchanged b128)
#pragma unroll
            for (int ks = 0; ks < 2; ks++) {
#pragma unroll
                for (int d = 0; d < 4; d++) {
                    const int vrow = d * 16 + col;
                    bvec8 vf = *(const bvec8*)&Vs[cur][vrow * 64 + (((ks * 4 + quad) ^ (vrow & 7)) * 8)];
                    o[d] = __builtin_amdgcn_mfma_f32_16x16x32_bf16(pbv[ks], vf, o[d], 0, 0, 0);
                }
            }
            asm volatile("s_barrier" ::: "memory");   // readers done before buf reuse
        }

        // l lives per-lane for Q-row = col: reduce across quads, then
        // redistribute to the O layout (rows quad*4+r) and store.
        float l = l_acc;
        l += __shfl_xor(l, 16);
        l += __shfl_xor(l, 32);
#pragma unroll
        for (int r = 0; r < 4; r++) {
            const float lr = __shfl(l, quad * 4 + r);   // lane quad*4+r holds row quad*4+r
            const float inv = 1.0f / lr;
            const int t = q0 + wave * 16 + quad * 4 + r;
#pragma unroll
            for (int d = 0; d < 4; d++)
                Y[(size_t)(b * 2048 + t) * 1024 + h * 64 + d * 16 + col] =
                    f32_to_bf16(o[d][r] * inv);
        }
    }
}

// ---------------------------------------------------------------------------
extern "C" void kernel_launch(void* const* d_in, const int* in_sizes, int n_in,
                              void* d_out, int out_size, void* d_ws, size_t ws_size,
                              hipStream_t stream) {
    const float* x      = (const float*)d_in[0];
    const float* w_attn = (const float*)d_in[1];
    const float* b_attn = (const float*)d_in[2];
    const float* w_proj = (const float*)d_in[3];
    const float* b_proj = (const float*)d_in[4];
    float* out = (float*)d_out;

    // ws (u16 elements): xb 4096x1024 | wab 3072x1024 | wpb 1024x1024 |
    //                    qkv 4096x3072 | y 4096x1024 ; vT overlays xb (dead after GEMM1)
    u16* xb  = (u16*)d_ws;
    u16* wab = xb  + (size_t)4096 * 1024;
    u16* wpb = wab + (size_t)3072 * 1024;
    u16* qkv = wpb + (size_t)1024 * 1024;
    u16* y   = qkv + (size_t)4096 * 3072;
    u16* vT  = xb;                               // reuse: 2*16*64*2048 = 4096*1024

    const int na4 = 4096 * 1024 / 4, nb4 = 3072 * 1024 / 4, nc4 = 1024 * 1024 / 4;
    cvt3<<<(na4 + nb4 + nc4 + 255) / 256, 256, 0, stream>>>(
        x, na4, w_attn, nb4, w_proj, nc4, xb, wab, wpb);

    dim3 g1(3072 / 128, 4096 / 128);
    gemm_bt_bias<128, true><<<g1, 256, 0, stream>>>(xb, wab, b_attn, qkv, 4096, 3072, 1024);

    dim3 gt(32, 16, 2);
    transpose_v<<<gt, 256, 0, stream>>>(qkv, vT);

    dim3 g2(32, 16, 1);   // x = b*16+h (XCD-local K/V), y = pair index
    attn_kernel<<<g2, 256, 0, stream>>>(qkv, vT, y);

    dim3 g3(1024 / 64, 4096 / 128);
    gemm_bt_bias<64, false><<<g3, 256, 0, stream>>>(y, wpb, b_proj, out, 4096, 1024, 1024);
}

// Round 4
// 176.301 us; speedup vs baseline: 1.0892x; 1.0293x over previous
//
#include <hip/hip_runtime.h>
#include <stdint.h>

typedef unsigned short u16;
typedef __attribute__((ext_vector_type(8))) __bf16 bvec8;
typedef __attribute__((ext_vector_type(4))) float f32x4;

__device__ __forceinline__ u16 f32_to_bf16(float f) {
    uint32_t u = __float_as_uint(f);
    u += 0x7fffu + ((u >> 16) & 1u);   // RNE
    return (u16)(u >> 16);
}

// async global->LDS, 16B/lane; LDS dest = wave-uniform base + lane*16 (HW rule)
__device__ __forceinline__ void gl2lds16(const u16* g, u16* l) {
    void* gnc = const_cast<void*>((const void*)g);
    __builtin_amdgcn_global_load_lds(
        (__attribute__((address_space(1))) uint32_t*)gnc,
        (__attribute__((address_space(3))) uint32_t*)((void*)l),
        16, 0, 0);
}

// ---------------------------------------------------------------------------
// fp32 -> bf16 for all three inputs in one launch
// ---------------------------------------------------------------------------
__global__ __launch_bounds__(256) void cvt3(
    const float* __restrict__ a, int na4, const float* __restrict__ b, int nb4,
    const float* __restrict__ c, int nc4,
    u16* __restrict__ oa, u16* __restrict__ ob, u16* __restrict__ oc)
{
    int i = blockIdx.x * 256 + threadIdx.x;
    const float* src; u16* dst; int off;
    if (i < na4)             { src = a; dst = oa; off = i; }
    else if (i < na4 + nb4)  { src = b; dst = ob; off = i - na4; }
    else if (i < na4 + nb4 + nc4) { src = c; dst = oc; off = i - na4 - nb4; }
    else return;
    float4 v = ((const float4*)src)[off];
    ushort4 o;
    o.x = f32_to_bf16(v.x); o.y = f32_to_bf16(v.y);
    o.z = f32_to_bf16(v.z); o.w = f32_to_bf16(v.w);
    ((ushort4*)dst)[off] = o;
}

// ---------------------------------------------------------------------------
// GEMM (B^T): C[M][N] = A[M][K]*B[N][K]^T + bias[N]; bf16 in, fp32 acc.
// BM=128, BK=32, BNt template (128 or 64). 256 thr = 4 waves as 2x2.
// Double-buffered (counted vmcnt, never 0 mid-loop).
// LDS CHUNK-XOR SWIZZLE: rows are 32 u16 = 4 x 16B chunks; chunk index is
// XOR'd with f(row) = (row&3)^((row>>2)&3) on BOTH sides (pre-swizzled
// global source for linear global_load_lds dest; same XOR on fragment
// reads). Spreads a quad-phase's 16 lanes 2-per-bank-slot (2-way = free)
// instead of the 8-way conflict of the linear layout (3.15M conflict-cyc
// in round-2 counters). Same fix that zeroed attn_kernel's conflicts.
// ---------------------------------------------------------------------------
template <int BNt, bool OUT_BF16>
__global__ __launch_bounds__(256) void gemm_bt_bias(
    const u16* __restrict__ A, const u16* __restrict__ B,
    const float* __restrict__ bias, void* __restrict__ Cv,
    int M, int N, int K)
{
    constexpr int NT = BNt / 32;                 // n-frags per wave
    __shared__ __attribute__((aligned(16))) u16 As[2][128 * 32];
    __shared__ __attribute__((aligned(16))) u16 Bs[2][BNt * 32];

    const int tid = threadIdx.x, wave = tid >> 6, lane = tid & 63;
    const int col = lane & 15, quad = lane >> 4;
    const int m0 = blockIdx.y * 128, n0 = blockIdx.x * BNt;
    const int wm = (wave >> 1) * 64, wn = (wave & 1) * (BNt / 2);
    const int srow = lane >> 2, schunk = lane & 3;
    // staging-side swizzle: LDS slot (row, c) gets global chunk c ^ f(row)
    const int fs = (srow & 3) ^ ((srow >> 2) & 3);
    const int sc = (schunk ^ fs) * 8;            // global chunk offset (u16)
    // read-side swizzle: lane reads row (…+col) at chunk quad ^ f(col)
    const int xsw = (quad ^ (col & 3) ^ ((col >> 2) & 3)) * 8;

    const u16* Ag = A + (size_t)(m0 + wave * 32) * K;
    const u16* Bg = B + (size_t)(n0 + wave * (BNt == 128 ? 32 : 16)) * K;

    f32x4 acc[4][NT];
#pragma unroll
    for (int i = 0; i < 4; i++)
#pragma unroll
        for (int j = 0; j < NT; j++) acc[i][j] = f32x4{0.f, 0.f, 0.f, 0.f};

    auto stage = [&](int bb, int k0) {
        gl2lds16(Ag + (size_t)(srow)      * K + k0 + sc, &As[bb][(wave * 2 + 0) * 512]);
        gl2lds16(Ag + (size_t)(16 + srow) * K + k0 + sc, &As[bb][(wave * 2 + 1) * 512]);
        if constexpr (BNt == 128) {
            gl2lds16(Bg + (size_t)(srow)      * K + k0 + sc, &Bs[bb][(wave * 2 + 0) * 512]);
            gl2lds16(Bg + (size_t)(16 + srow) * K + k0 + sc, &Bs[bb][(wave * 2 + 1) * 512]);
        } else {
            gl2lds16(Bg + (size_t)(srow)      * K + k0 + sc, &Bs[bb][wave * 512]);
        }
    };

    // prologue: tile 0 into buffer 0
    stage(0, 0);
    const int NS = K / 32;

    for (int t = 0; t < NS; ++t) {
        const int cur = t & 1;
        if (t + 1 < NS) {
            stage(cur ^ 1, (t + 1) * 32);
            if constexpr (BNt == 128) asm volatile("s_waitcnt vmcnt(4)" ::: "memory");
            else                      asm volatile("s_waitcnt vmcnt(3)" ::: "memory");
        } else {
            asm volatile("s_waitcnt vmcnt(0)" ::: "memory");
        }
        asm volatile("s_barrier" ::: "memory");     // cur tile visible to all waves

        bvec8 af[4], bfv[NT];
#pragma unroll
        for (int mt = 0; mt < 4; mt++)  af[mt]  = *(const bvec8*)&As[cur][(wm + mt * 16 + col) * 32 + xsw];
#pragma unroll
        for (int nt = 0; nt < NT; nt++) bfv[nt] = *(const bvec8*)&Bs[cur][(wn + nt * 16 + col) * 32 + xsw];
#pragma unroll
        for (int mt = 0; mt < 4; mt++)
#pragma unroll
            for (int nt = 0; nt < NT; nt++)
                acc[mt][nt] = __builtin_amdgcn_mfma_f32_16x16x32_bf16(af[mt], bfv[nt], acc[mt][nt], 0, 0, 0);

        asm volatile("s_barrier" ::: "memory");     // readers done before buf reuse
    }

#pragma unroll
    for (int mt = 0; mt < 4; mt++) {
#pragma unroll
        for (int r = 0; r < 4; r++) {
            const int m = m0 + wm + mt * 16 + quad * 4 + r;
#pragma unroll
            for (int nt = 0; nt < NT; nt++) {
                const int n = n0 + wn + nt * 16 + col;
                float v = acc[mt][nt][r] + bias[n];
                if (OUT_BF16) ((u16*)Cv)[(size_t)m * N + n] = f32_to_bf16(v);
                else          ((float*)Cv)[(size_t)m * N + n] = v;
            }
        }
    }
}

// ---------------------------------------------------------------------------
// V transpose: qkv V-region [b][t][h*64+d] -> vT[b][h][d][t]  (bf16)
// ---------------------------------------------------------------------------
__global__ __launch_bounds__(256) void transpose_v(const u16* __restrict__ qkv,
                                                   u16* __restrict__ vT)
{
    __shared__ u16 Ts[64 * 74];
    const int tid = threadIdx.x;
    const int t0 = blockIdx.x * 64, h = blockIdx.y, b = blockIdx.z;
    const u16* src = qkv + (size_t)b * 2048 * 3072 + 2048 + h * 64;
#pragma unroll
    for (int k2 = 0; k2 < 2; k2++) {
        int c = k2 * 256 + tid, tl = c >> 3, ch = c & 7;
        *(uint4*)&Ts[tl * 74 + ch * 8] = *(const uint4*)(src + (size_t)(t0 + tl) * 3072 + ch * 8);
    }
    __syncthreads();
    u16* dst = vT + (size_t)((b * 16 + h) * 64) * 2048;
#pragma unroll
    for (int k2 = 0; k2 < 2; k2++) {
        int c = k2 * 256 + tid, d = c >> 3, tch = c & 7;
        u16 tmp[8];
#pragma unroll
        for (int j2 = 0; j2 < 8; j2++) tmp[j2] = Ts[(tch * 8 + j2) * 74 + d];
        *(uint4*)&dst[(size_t)d * 2048 + t0 + tch * 8] = *(const uint4*)tmp;
    }
}

// ---------------------------------------------------------------------------
// Flash attention, no-max softmax. Complementary pair (s,31-s) per block.
// Grid (32,16,1): x = b*16+h  =>  all 16 blocks of a head share one XCD
// (linear%8 = x%8) so K/V live in that XCD's L2.
// K/V double-buffered via global_load_lds + raw s_barrier/s_waitcnt vmcnt(4).
//
// REGISTER-P VERSION: S^T = mfma(K,Q) so each lane holds P for ONE Q-row
// (col) at staged-K rows nt*16+quad*4+r. K staging rows are permuted by
//   tau(16a+4q+r) = 32*(a>>1) + 8q + 4*(a&1) + r
// so the lane's 16 P values are exactly the A-fragment k-slots
// (ks*32+quad*8+j) that the unchanged b128 V fragments expect.
// P->bf16 via plain compiler casts (backend emits correct RNE cvt_pk;
// hand-written asm cvt_pk was the round-1 correctness bug and is also
// slower per guide m240). P never touches LDS.
// ---------------------------------------------------------------------------
__global__ __launch_bounds__(256) void attn_kernel(const u16* __restrict__ qkv,
                                                   const u16* __restrict__ vT,
                                                   u16* __restrict__ Y)
{
    __shared__ __attribute__((aligned(16))) u16 Qs[64 * 64];
    __shared__ __attribute__((aligned(16))) u16 Ks[2][64 * 64];
    __shared__ __attribute__((aligned(16))) u16 Vs[2][64 * 64];

    const int tid = threadIdx.x, wave = tid >> 6, lane = tid & 63;
    const int col = lane & 15, quad = lane >> 4;

    const int g = blockIdx.x;                // b*16 + h
    const int b = g >> 4, h = g & 15;
    const int s_idx = blockIdx.y;            // pair (s_idx, 31-s_idx)

    const u16* qb = qkv + (size_t)b * 2048 * 3072;
    const u16* vb = vT + (size_t)g * 64 * 2048;

    // per-lane swizzled source params for the 2 staging calls per tile
    const int c0 = wave * 64 + lane, c1 = 256 + c0;
    const int r0 = c0 >> 3, p0 = c0 & 7, r1 = c1 >> 3, p1 = c1 & 7;
    const int sw0 = (p0 ^ (r0 & 7)) * 8, sw1 = (p1 ^ (r1 & 7)) * 8;
    // K-row staging permutation: staged row rho holds logical row tau(rho)
    const int tau0 = (r0 & 32) | ((r0 & 12) << 1) | ((r0 & 16) >> 2) | (r0 & 3);
    const int tau1 = (r1 & 32) | ((r1 & 12) << 1) | ((r1 & 16) >> 2) | (r1 & 3);

    const int q8 = quad * 8;
    const int qit = wave * 16 + col;         // in-tile Q row this lane owns

#pragma unroll
    for (int phase = 0; phase < 2; ++phase) {
        const int qt = phase ? (31 - s_idx) : s_idx;
        const int q0 = qt * 64;

        __syncthreads();   // phase-0 readers done; also drains Y stores
        gl2lds16(qb + (size_t)(q0 + r0) * 3072 + h * 64 + sw0, &Qs[wave * 512]);
        gl2lds16(qb + (size_t)(q0 + r1) * 3072 + h * 64 + sw1, &Qs[2048 + wave * 512]);
        __syncthreads();   // Q visible to all waves

        const int qrow = wave * 16 + col;
        bvec8 qf0 = *(const bvec8*)&Qs[qrow * 64 + ((quad       ^ (qrow & 7)) * 8)];
        bvec8 qf1 = *(const bvec8*)&Qs[qrow * 64 + (((4 + quad) ^ (qrow & 7)) * 8)];

        float l_acc = 0.f;
        f32x4 o[4];
#pragma unroll
        for (int d = 0; d < 4; d++) o[d] = f32x4{0.f, 0.f, 0.f, 0.f};

        // prologue: issue tile 0 into buffer 0 (K rows tau-permuted)
        {
            gl2lds16(qb + (size_t)(tau0) * 3072 + 1024 + h * 64 + sw0, &Ks[0][wave * 512]);
            gl2lds16(qb + (size_t)(tau1) * 3072 + 1024 + h * 64 + sw1, &Ks[0][2048 + wave * 512]);
            gl2lds16(vb + (size_t)r0 * 2048 + sw0, &Vs[0][wave * 512]);
            gl2lds16(vb + (size_t)r1 * 2048 + sw1, &Vs[0][2048 + wave * 512]);
        }

        for (int kt = 0; kt <= qt; ++kt) {
            const int cur = kt & 1;
            if (kt < qt) {
                const int s0n = (kt + 1) * 64;
                const int nb2 = cur ^ 1;
                gl2lds16(qb + (size_t)(s0n + tau0) * 3072 + 1024 + h * 64 + sw0, &Ks[nb2][wave * 512]);
                gl2lds16(qb + (size_t)(s0n + tau1) * 3072 + 1024 + h * 64 + sw1, &Ks[nb2][2048 + wave * 512]);
                gl2lds16(vb + (size_t)r0 * 2048 + s0n + sw0, &Vs[nb2][wave * 512]);
                gl2lds16(vb + (size_t)r1 * 2048 + s0n + sw1, &Vs[nb2][2048 + wave * 512]);
                asm volatile("s_waitcnt vmcnt(4)" ::: "memory");   // cur tile landed; next in flight
            } else {
                asm volatile("s_waitcnt vmcnt(0)" ::: "memory");   // last tile landed
            }
            asm volatile("s_barrier" ::: "memory");                 // all waves see cur tile

            // S^T = K Q^T : lane (quad,col) reg r of sv[nt] =
            //   S[q = wave*16+col][staged k = nt*16+quad*4+r]
            f32x4 sv[4];
#pragma unroll
            for (int nt = 0; nt < 4; nt++) {
                const int krow = nt * 16 + col;
                bvec8 kf0 = *(const bvec8*)&Ks[cur][krow * 64 + ((quad       ^ (krow & 7)) * 8)];
                bvec8 kf1 = *(const bvec8*)&Ks[cur][krow * 64 + (((4 + quad) ^ (krow & 7)) * 8)];
                sv[nt] = f32x4{0.f, 0.f, 0.f, 0.f};
                sv[nt] = __builtin_amdgcn_mfma_f32_16x16x32_bf16(kf0, qf0, sv[nt], 0, 0, 0);
                sv[nt] = __builtin_amdgcn_mfma_f32_16x16x32_bf16(kf1, qf1, sv[nt], 0, 0, 0);
            }

            // no-max softmax in registers: p = exp(S/8); mask diag by LOGICAL k.
            // Element j of pbv[ks] must be P[q=col][t = ks*32 + quad*8 + j]:
            // nt=2ks  -> j = r      (klog = ks*32 + quad*8 + r)
            // nt=2ks+1-> j = 4 + r  (klog = ks*32 + quad*8 + 4 + r)
            const bool diag = (kt == qt);
            bvec8 pbv[2];
#pragma unroll
            for (int nt = 0; nt < 4; nt++) {
#pragma unroll
                for (int r = 0; r < 4; r++) {
                    float p = __expf(sv[nt][r] * 0.125f);
                    const int klog = 32 * (nt >> 1) + q8 + 4 * (nt & 1) + r;
                    if (diag && klog > qit) p = 0.f;
                    l_acc += p;
                    pbv[nt >> 1][(nt & 1) * 4 + r] = (__bf16)p;
                }
            }

            // O += P V   (P straight from registers; V reads unchanged b128)
#pragma unroll
            for (int ks = 0; ks < 2; ks++) {
#pragma unroll
                for (int d = 0; d < 4; d++) {
                    const int vrow = d * 16 + col;
                    bvec8 vf = *(const bvec8*)&Vs[cur][vrow * 64 + (((ks * 4 + quad) ^ (vrow & 7)) * 8)];
                    o[d] = __builtin_amdgcn_mfma_f32_16x16x32_bf16(pbv[ks], vf, o[d], 0, 0, 0);
                }
            }
            asm volatile("s_barrier" ::: "memory");   // readers done before buf reuse
        }

        // l lives per-lane for Q-row = col: reduce across quads, then
        // redistribute to the O layout (rows quad*4+r) and store.
        float l = l_acc;
        l += __shfl_xor(l, 16);
        l += __shfl_xor(l, 32);
#pragma unroll
        for (int r = 0; r < 4; r++) {
            const float lr = __shfl(l, quad * 4 + r);   // lane quad*4+r holds row quad*4+r
            const float inv = 1.0f / lr;
            const int t = q0 + wave * 16 + quad * 4 + r;
#pragma unroll
            for (int d = 0; d < 4; d++)
                Y[(size_t)(b * 2048 + t) * 1024 + h * 64 + d * 16 + col] =
                    f32_to_bf16(o[d][r] * inv);
        }
    }
}

// ---------------------------------------------------------------------------
extern "C" void kernel_launch(void* const* d_in, const int* in_sizes, int n_in,
                              void* d_out, int out_size, void* d_ws, size_t ws_size,
                              hipStream_t stream) {
    const float* x      = (const float*)d_in[0];
    const float* w_attn = (const float*)d_in[1];
    const float* b_attn = (const float*)d_in[2];
    const float* w_proj = (const float*)d_in[3];
    const float* b_proj = (const float*)d_in[4];
    float* out = (float*)d_out;

    // ws (u16 elements): xb 4096x1024 | wab 3072x1024 | wpb 1024x1024 |
    //                    qkv 4096x3072 | y 4096x1024 ; vT overlays xb (dead after GEMM1)
    u16* xb  = (u16*)d_ws;
    u16* wab = xb  + (size_t)4096 * 1024;
    u16* wpb = wab + (size_t)3072 * 1024;
    u16* qkv = wpb + (size_t)1024 * 1024;
    u16* y   = qkv + (size_t)4096 * 3072;
    u16* vT  = xb;                               // reuse: 2*16*64*2048 = 4096*1024

    const int na4 = 4096 * 1024 / 4, nb4 = 3072 * 1024 / 4, nc4 = 1024 * 1024 / 4;
    cvt3<<<(na4 + nb4 + nc4 + 255) / 256, 256, 0, stream>>>(
        x, na4, w_attn, nb4, w_proj, nc4, xb, wab, wpb);

    dim3 g1(3072 / 128, 4096 / 128);
    gemm_bt_bias<128, true><<<g1, 256, 0, stream>>>(xb, wab, b_attn, qkv, 4096, 3072, 1024);

    dim3 gt(32, 16, 2);
    transpose_v<<<gt, 256, 0, stream>>>(qkv, vT);

    dim3 g2(32, 16, 1);   // x = b*16+h (XCD-local K/V), y = pair index
    attn_kernel<<<g2, 256, 0, stream>>>(qkv, vT, y);

    dim3 g3(1024 / 64, 4096 / 128);
    gemm_bt_bias<64, false><<<g3, 256, 0, stream>>>(y, wpb, b_proj, out, 4096, 1024, 1024);
}